// Round 1
// baseline (98.101 us; speedup 1.0000x reference)
//
#include <hip/hip_runtime.h>

#define IMG_W 1024
#define IMG_H 1024
#define NFRAMES 32
#define CROP 4
#define RPB 32   // output rows per block

__device__ __forceinline__ float4 ldg4(const float* p) {
    return *reinterpret_cast<const float4*>(p);
}

__global__ __launch_bounds__(256) void gimbaless_sums(
    const float* __restrict__ A, const float* __restrict__ B,
    const float* __restrict__ lp9, double* __restrict__ sums)
{
    const int tid = threadIdx.x;
    const int v = blockIdx.x;   // vertical strip
    const int t = blockIdx.y;   // frame
    const size_t frame_off = (size_t)t * (IMG_W * IMG_H);
    const float* a = A + frame_off;
    const float* b = B + frame_off;

    float lp[9];
#pragma unroll
    for (int k = 0; k < 9; ++k) lp[k] = lp9[k];

    float s0=0.f,s1=0.f,s2=0.f,s3=0.f,s4=0.f,s5=0.f,s6=0.f,s7=0.f,s8=0.f;

    const int r0 = CROP + v * RPB;
    const int rend = min(r0 + RPB, IMG_H - CROP);
    const bool active = (tid >= 1 && tid <= 254);

    if (active) {
        const int w0 = 4 * tid;                 // columns w0..w0+3
        const float* ap = a + w0;
        const float* bp = b + w0;

        float d[9][4];    // dif rows h-4 .. h+4 (d[8] filled in-loop)
        float av[6][4];   // avg rows h-1 .. h+4 (av[5] filled in-loop)

        // preload rows r0-4 .. r0+3 into d[0..7]; avg of rows r0-1..r0+3 into av[0..4]
#pragma unroll
        for (int k = 0; k < 8; ++k) {
            const int r = r0 - 4 + k;
            float4 va = ldg4(ap + (size_t)r * IMG_W);
            float4 vb = ldg4(bp + (size_t)r * IMG_W);
            d[k][0] = va.x - vb.x; d[k][1] = va.y - vb.y;
            d[k][2] = va.z - vb.z; d[k][3] = va.w - vb.w;
            if (k >= 3) {
                av[k-3][0] = (va.x + vb.x) * 0.5f;
                av[k-3][1] = (va.y + vb.y) * 0.5f;
                av[k-3][2] = (va.z + vb.z) * 0.5f;
                av[k-3][3] = (va.w + vb.w) * 0.5f;
            }
        }

        for (int h = r0; h < rend; ++h) {
            // insert row h+4 (narrow)
            {
                float4 na = ldg4(ap + (size_t)(h + 4) * IMG_W);
                float4 nb = ldg4(bp + (size_t)(h + 4) * IMG_W);
                d[8][0] = na.x - nb.x; d[8][1] = na.y - nb.y;
                d[8][2] = na.z - nb.z; d[8][3] = na.w - nb.w;
                av[5][0] = (na.x + nb.x) * 0.5f;
                av[5][1] = (na.y + nb.y) * 0.5f;
                av[5][2] = (na.z + nb.z) * 0.5f;
                av[5][3] = (na.w + nb.w) * 0.5f;
            }
            // side halos at row h: columns w0-4..w0-1 and w0+4..w0+7
            float dc[12];
            float avgL, avgR;
            {
                const size_t ro = (size_t)h * IMG_W;
                float4 la = ldg4(ap + ro - 4);
                float4 lb = ldg4(bp + ro - 4);
                float4 ra = ldg4(ap + ro + 4);
                float4 rb = ldg4(bp + ro + 4);
                dc[0] = la.x - lb.x; dc[1] = la.y - lb.y;
                dc[2] = la.z - lb.z; dc[3] = la.w - lb.w;
                dc[4] = d[4][0]; dc[5] = d[4][1]; dc[6] = d[4][2]; dc[7] = d[4][3];
                dc[8]  = ra.x - rb.x; dc[9]  = ra.y - rb.y;
                dc[10] = ra.z - rb.z; dc[11] = ra.w - rb.w;
                avgL = (la.w + lb.w) * 0.5f;   // avg at w0-1
                avgR = (ra.x + rb.x) * 0.5f;   // avg at w0+4
            }
            // avg row h extended: w0-1 .. w0+4
            float avc[6];
            avc[0] = avgL;
            avc[1] = av[1][0]; avc[2] = av[1][1];
            avc[3] = av[1][2]; avc[4] = av[1][3];
            avc[5] = avgR;

            const float y = (float)h - 511.5f;
#pragma unroll
            for (int j = 0; j < 4; ++j) {
                float px = (avc[j] - avc[j + 2]) * 0.5f;
                float py = (av[0][j] - av[2][j]) * 0.5f;
                float ax = 0.f, ay = 0.f;
#pragma unroll
                for (int k = 0; k < 9; ++k) {
                    ax = fmaf(lp[k], dc[j + k], ax);
                    ay = fmaf(lp[k], d[k][j], ay);
                }
                const float x = (float)(w0 + j) - 511.5f;
                const float mom = px * y - py * x;
                s0 = fmaf(px, px, s0);
                s1 = fmaf(px, py, s1);
                s2 = fmaf(px, mom, s2);
                s3 = fmaf(py, py, s3);
                s4 = fmaf(py, mom, s4);
                s5 = fmaf(mom, mom, s5);
                const float tx = ax * px;
                const float ty = ay * py;
                s6 += tx;
                s7 += ty;
                s8 += tx * y - ty * x;
            }
            // shift windows
#pragma unroll
            for (int k = 0; k < 8; ++k) {
                d[k][0] = d[k+1][0]; d[k][1] = d[k+1][1];
                d[k][2] = d[k+1][2]; d[k][3] = d[k+1][3];
            }
#pragma unroll
            for (int k = 0; k < 5; ++k) {
                av[k][0] = av[k+1][0]; av[k][1] = av[k+1][1];
                av[k][2] = av[k+1][2]; av[k][3] = av[k+1][3];
            }
        }
    }

    // ---- reduction: f64 wave shuffle -> LDS -> global atomic ----
    double ds[9];
    ds[0]=s0; ds[1]=s1; ds[2]=s2; ds[3]=s3; ds[4]=s4;
    ds[5]=s5; ds[6]=s6; ds[7]=s7; ds[8]=s8;
#pragma unroll
    for (int k = 0; k < 9; ++k) {
        double x = ds[k];
        for (int off = 32; off > 0; off >>= 1)
            x += __shfl_down(x, off);
        ds[k] = x;
    }
    __shared__ double red[4][9];
    const int wave = tid >> 6, lane = tid & 63;
    if (lane == 0) {
#pragma unroll
        for (int k = 0; k < 9; ++k) red[wave][k] = ds[k];
    }
    __syncthreads();
    if (tid < 9) {
        double tot = red[0][tid] + red[1][tid] + red[2][tid] + red[3][tid];
        atomicAdd(&sums[(size_t)t * 9 + tid], tot);
    }
}

__global__ void gimbaless_solve(const double* __restrict__ sums, float* __restrict__ out)
{
    const int t = threadIdx.x;
    if (t < NFRAMES) {
        const double* s = sums + (size_t)t * 9;
        const double m00=s[0], m01=s[1], m02=s[2], m11=s[3], m12=s[4], m22=s[5];
        const double b0=s[6], b1=s[7], b2=s[8];
        const double c00 = m11*m22 - m12*m12;
        const double c01 = m02*m12 - m01*m22;
        const double c02 = m01*m12 - m02*m11;
        const double c11 = m00*m22 - m02*m02;
        const double c12 = m01*m02 - m00*m12;
        const double c22 = m00*m11 - m01*m01;
        const double det = m00*c00 + m01*c01 + m02*c02;
        const double inv = 1.0 / det;
        out[t]              = (float)((c00*b0 + c01*b1 + c02*b2) * inv);
        out[NFRAMES + t]    = (float)((c01*b0 + c11*b1 + c12*b2) * inv);
        out[2*NFRAMES + t]  = (float)((c02*b0 + c12*b1 + c22*b2) * inv);
    }
}

extern "C" void kernel_launch(void* const* d_in, const int* in_sizes, int n_in,
                              void* d_out, int out_size, void* d_ws, size_t ws_size,
                              hipStream_t stream) {
    const float* A  = (const float*)d_in[0];
    const float* B  = (const float*)d_in[1];
    const float* lp = (const float*)d_in[2];
    double* sums = (double*)d_ws;

    hipMemsetAsync(d_ws, 0, NFRAMES * 9 * sizeof(double), stream);

    dim3 grid((IMG_H - 2*CROP + RPB - 1) / RPB, NFRAMES);  // (32, 32)
    gimbaless_sums<<<grid, 256, 0, stream>>>(A, B, lp, sums);
    gimbaless_solve<<<1, 64, 0, stream>>>(sums, (float*)d_out);
}